// Round 15
// baseline (193.445 us; speedup 1.0000x reference)
//
#include <hip/hip_runtime.h>
#include <hip/hip_bf16.h>
#include <math.h>

#define B_ 4
#define T_ 2048
#define DM 768
#define H_ 12
#define DH 64

typedef __attribute__((ext_vector_type(4))) float f32x4;
typedef __attribute__((ext_vector_type(8))) short s16x8;

typedef const __attribute__((address_space(1))) void* gas1_t;
typedef __attribute__((address_space(3))) void* las3_t;

__device__ __forceinline__ ushort f2b(float f) {
  union { float f; unsigned u; } v; v.f = f;
  unsigned u = v.u;
  u += 0x7fffu + ((u >> 16) & 1u);
  return (ushort)(u >> 16);
}
// packed f32x2 -> bf16x2 (RNE, same rounding as f2b) in one instruction
__device__ __forceinline__ unsigned cvt_pk_bf16(float lo, float hi) {
  unsigned r;
  asm("v_cvt_pk_bf16_f32 %0, %1, %2" : "=v"(r) : "v"(lo), "v"(hi));
  return r;
}

// ---------------- fused fp32->bf16 conversions + rope pack, one launch ----------------
__global__ void cvt_all(const float* __restrict__ x,
                        const float* __restrict__ wq, const float* __restrict__ wk,
                        const float* __restrict__ wv, const float* __restrict__ wo,
                        const float* __restrict__ rc, const float* __restrict__ rs,
                        ushort* __restrict__ xb, ushort* __restrict__ wqkv,
                        ushort* __restrict__ wob, float2* __restrict__ cs2) {
  const int bid = blockIdx.x, t = threadIdx.x;
  if (bid < 6144) {
    int i = bid * 256 + t;
    float4 v = ((const float4*)x)[i];
    ushort4 o;
    o.x = f2b(v.x); o.y = f2b(v.y); o.z = f2b(v.z); o.w = f2b(v.w);
    ((ushort4*)xb)[i] = o;
  } else if (bid < 8448) {
    int i = (bid - 6144) * 256 + t;  // 0 .. 589823
    int which = i / 147456, j = i - which * 147456;
    const float* src = which == 0 ? wq : which == 1 ? wk : which == 2 ? wv : wo;
    ushort* dst = which < 3 ? wqkv + (size_t)which * 589824 : wob;
    float4 v = ((const float4*)src)[j];
    ushort4 o;
    o.x = f2b(v.x); o.y = f2b(v.y); o.z = f2b(v.z); o.w = f2b(v.w);
    ((ushort4*)dst)[j] = o;
  } else {
    int i = (bid - 8448) * 256 + t;  // 0 .. 65535
    cs2[i] = make_float2(rc[i], rs[i]);
  }
}

// ---------------- QKV GEMM: 128x192 tiles, BK=64, grid 768 = 3/CU exact ----------------
// 768 = 8 XCD x 8 m-panels x 12 n-panels(192). 48 MFMA per barrier pair.
// A staged via global_load_lds from bf16 xb (reg-staged f32 variant was -22us).
__global__ __launch_bounds__(256, 3) void gemm_qkv(
    const ushort* __restrict__ A, const ushort* __restrict__ Bw,
    const float2* __restrict__ cs2,
    ushort* __restrict__ Qb, ushort* __restrict__ Kb, ushort* __restrict__ Vt) {
  const int K = 768;
  __shared__ ushort As[128 * 64];
  __shared__ ushort Bs[192 * 64];
  const int bid = blockIdx.x;
  const int xcd = bid & 7;
  const int jj = bid >> 3;               // 0..95
  const int mloc = jj / 12, nn0 = jj - mloc * 12;
  const int m0 = (xcd * 8 + mloc) * 128, n0 = nn0 * 192;
  const int tid = threadIdx.x;
  const int wave = tid >> 6, lane = tid & 63;
  const int wm = (wave >> 1) * 64, wn = (wave & 1) * 96;
  const int quad = lane >> 4, l16 = lane & 15;
  const int tr = tid >> 3;                 // staging row 0..31 (per 32-row pass)
  const int scb = (tid & 7) ^ (tr & 7);    // pre-swizzled source colblock
  const int swz = l16 & 7;                 // frag-read swizzle term (= row&7)

  f32x4 acc[4][6] = {};

  const ushort* ga = A + (size_t)(m0 + tr) * K + scb * 8;
  const ushort* gb = Bw + (size_t)(n0 + tr) * K + scb * 8;

  for (int k0 = 0; k0 < K; k0 += 64) {
#pragma unroll
    for (int p = 0; p < 4; p++)
      __builtin_amdgcn_global_load_lds((gas1_t)(ga + (size_t)(p * 32) * K + k0),
                                       (las3_t)(As + p * 2048 + tid * 8), 16, 0, 0);
#pragma unroll
    for (int p = 0; p < 6; p++)
      __builtin_amdgcn_global_load_lds((gas1_t)(gb + (size_t)(p * 32) * K + k0),
                                       (las3_t)(Bs + p * 2048 + tid * 8), 16, 0, 0);
    __syncthreads();
#pragma unroll
    for (int kk = 0; kk < 2; kk++) {
      s16x8 af[4], bf[6];
#pragma unroll
      for (int i = 0; i < 4; i++) {
        const ushort* ar = As + (wm + i * 16 + l16) * 64;
        af[i] = *(const s16x8*)(ar + (((kk * 4 + quad) ^ swz) * 8));
      }
#pragma unroll
      for (int n = 0; n < 6; n++) {
        const ushort* br = Bs + (wn + n * 16 + l16) * 64;
        bf[n] = *(const s16x8*)(br + (((kk * 4 + quad) ^ swz) * 8));
      }
#pragma unroll
      for (int i = 0; i < 4; i++)
#pragma unroll
        for (int n = 0; n < 6; n++)
          acc[i][n] = __builtin_amdgcn_mfma_f32_16x16x32_bf16(af[i], bf[n], acc[i][n], 0, 0, 0);
    }
    __syncthreads();
  }

  const int sec = n0 / 768;  // 0=q, 1=k, 2=v (uniform per block; 768 = 4*192)
  if (sec < 2) {
    ushort* dst = sec == 0 ? Qb : Kb;
#pragma unroll
    for (int i = 0; i < 4; i++) {
      int row0 = m0 + wm + i * 16 + quad * 4;
#pragma unroll
      for (int nt = 0; nt < 6; nt++) {
        int col = n0 + wn + nt * 16 + l16;
        int nv = col - sec * 768;
        int h = nv >> 6, d = nv & 63;
        int ip = (d >> 1) & 31;
        float sgn = (d & 1) ? 1.f : -1.f;
#pragma unroll
        for (int r = 0; r < 4; r++) {
          int rrow = row0 + r;
          int t = rrow & (T_ - 1), bb = rrow >> 11;
          float v = acc[i][nt][r];
          float partner = __shfl_xor(v, 1);
          float2 cs = cs2[t * 32 + ip];
          float out = fmaf(v, cs.x, sgn * partner * cs.y);
          dst[((size_t)(bb * H_ + h) * T_ + t) * DH + d] = f2b(out);
        }
      }
    }
  } else {
#pragma unroll
    for (int i = 0; i < 4; i++) {
      int row0 = m0 + wm + i * 16 + quad * 4;
      int t0 = row0 & (T_ - 1), b = row0 >> 11;  // 4 rows share b (aligned)
#pragma unroll
      for (int nt = 0; nt < 6; nt++) {
        int col = n0 + wn + nt * 16 + l16;
        int nv = col - 1536;
        int h = nv >> 6, d = nv & 63;
        ushort4 pk;
        pk.x = f2b(acc[i][nt][0]); pk.y = f2b(acc[i][nt][1]);
        pk.z = f2b(acc[i][nt][2]); pk.w = f2b(acc[i][nt][3]);
        *(ushort4*)(Vt + ((size_t)(b * H_ + h) * DH + d) * T_ + t0) = pk;
      }
    }
  }
}

// ---------------- output GEMM: 128x64 tiles, BK=64, grid 768 = 3/CU exact ----------------
// 768 = 8 XCD x 8 m x 12 n(64). Occupancy-parity with gemm_qkv (was 2/CU at
// 128x96/512 blocks; exact-fill 3/CU was the session's most reliable lever).
__global__ __launch_bounds__(256, 3) void gemm_out(
    const ushort* __restrict__ A, const ushort* __restrict__ Bw, float* __restrict__ C) {
  const int K = 768, N = 768;
  __shared__ ushort As[128 * 64];
  __shared__ ushort Bs[64 * 64];
  const int bid = blockIdx.x;
  const int xcd = bid & 7;
  const int jj = bid >> 3;               // 0..95
  const int mloc = jj / 12, nn0 = jj - mloc * 12;
  const int m0 = (xcd * 8 + mloc) * 128, n0 = nn0 * 64;
  const int tid = threadIdx.x;
  const int wave = tid >> 6, lane = tid & 63;
  const int wm = (wave >> 1) * 64, wn = (wave & 1) * 32;
  const int quad = lane >> 4, l16 = lane & 15;
  const int tr = tid >> 3;
  const int scb = (tid & 7) ^ (tr & 7);
  const int swz = l16 & 7;

  f32x4 acc[4][2] = {};

  const ushort* ga = A + (size_t)(m0 + tr) * K + scb * 8;
  const ushort* gb = Bw + (size_t)(n0 + tr) * K + scb * 8;

  for (int k0 = 0; k0 < K; k0 += 64) {
#pragma unroll
    for (int p = 0; p < 4; p++)
      __builtin_amdgcn_global_load_lds((gas1_t)(ga + (size_t)(p * 32) * K + k0),
                                       (las3_t)(As + p * 2048 + tid * 8), 16, 0, 0);
#pragma unroll
    for (int p = 0; p < 2; p++)
      __builtin_amdgcn_global_load_lds((gas1_t)(gb + (size_t)(p * 32) * K + k0),
                                       (las3_t)(Bs + p * 2048 + tid * 8), 16, 0, 0);
    __syncthreads();
#pragma unroll
    for (int kk = 0; kk < 2; kk++) {
      s16x8 af[4], bf[2];
#pragma unroll
      for (int i = 0; i < 4; i++) {
        const ushort* ar = As + (wm + i * 16 + l16) * 64;
        af[i] = *(const s16x8*)(ar + (((kk * 4 + quad) ^ swz) * 8));
      }
#pragma unroll
      for (int n = 0; n < 2; n++) {
        const ushort* br = Bs + (wn + n * 16 + l16) * 64;
        bf[n] = *(const s16x8*)(br + (((kk * 4 + quad) ^ swz) * 8));
      }
#pragma unroll
      for (int i = 0; i < 4; i++)
#pragma unroll
        for (int n = 0; n < 2; n++)
          acc[i][n] = __builtin_amdgcn_mfma_f32_16x16x32_bf16(af[i], bf[n], acc[i][n], 0, 0, 0);
    }
    __syncthreads();
  }

#pragma unroll
  for (int i = 0; i < 4; i++) {
    int row = m0 + wm + i * 16 + quad * 4;
#pragma unroll
    for (int n = 0; n < 2; n++) {
      int col = n0 + wn + n * 16 + l16;
#pragma unroll
      for (int r = 0; r < 4; r++)
        C[(size_t)(row + r) * N + col] = acc[i][n][r];
    }
  }
}

// ---------------- causal flash attention v16: sequential pairing, 0 idle waves ----------------
// Block (bh,p) processes 64-row tile p FULLY (kv 0..p), epilogue, then tile
// 31-p fully. Each wave owns 16 rows (1 m-frag) -> all 4 waves compute in
// EVERY iteration. 33 iterations for all p; serial chain 16 MFMA/iter vs
// v11's 32. Measured: 52.4 us, MfmaUtil 19.8, VGPR 68, WRITE clean.
// Bans hold: setprio, O^T epilogue, psw-on-2-frag, (256,4) bounds.
#define EXP2SCALE 0.18033688f   /* 0.125 * log2(e) */
#define EXP2OFF  17.312340f     /* 12 * log2(e) */
__global__ __launch_bounds__(256, 3) void attn(const ushort* __restrict__ Qb, const ushort* __restrict__ Kb,
                                               const ushort* __restrict__ Vt, ushort* __restrict__ Ob) {
  const int bh = blockIdx.x;
  const int p = blockIdx.y;        // pair index 0..15: tiles p then 31-p
  const int tid = threadIdx.x, wave = tid >> 6, lane = tid & 63;
  const int quad = lane >> 4, l16 = lane & 15;
  const int b = bh / H_, h = bh % H_;
  const ushort* Qp = Qb + (size_t)bh * T_ * DH;
  const ushort* Kp = Kb + (size_t)bh * T_ * DH;
  const ushort* Vp = Vt + (size_t)bh * DH * T_;

  __shared__ ushort Ks[2][64 * 64];
  __shared__ ushort Vs[2][64 * 64];
  __shared__ ushort P[4][16][72];   // per wave; row = q (l16), col = kv

  const int srow = tid >> 3;                   // 0..31
  const int scbK = (tid & 7) ^ (srow & 7);     // swizzled source colblock
  const int swz = (l16 & 7);

#pragma unroll
  for (int phase = 0; phase < 2; phase++) {
    const int tile = phase ? (31 - p) : p;     // 64-row q tile
    const int qb = tile * 64 + wave * 16;      // this wave's 16 rows

    s16x8 aq0, aq1;
    {
      const ushort* qp = Qp + (size_t)(qb + l16) * DH + quad * 8;
      aq0 = *(const s16x8*)qp;
      aq1 = *(const s16x8*)(qp + 32);
    }
    f32x4 o[4] = {};
    float rsum = 0.f;
    const int ntile = tile + 1;  // kv tiles 0..tile

    __syncthreads();  // previous phase's LDS readers done before restaging
    {
      const int kv0 = 0;
      __builtin_amdgcn_global_load_lds((gas1_t)(Kp + (size_t)(kv0 + srow) * DH + scbK * 8),
                                       (las3_t)(Ks[0] + tid * 8), 16, 0, 0);
      __builtin_amdgcn_global_load_lds((gas1_t)(Kp + (size_t)(kv0 + srow + 32) * DH + scbK * 8),
                                       (las3_t)(Ks[0] + 2048 + tid * 8), 16, 0, 0);
      __builtin_amdgcn_global_load_lds((gas1_t)(Vp + (size_t)srow * T_ + kv0 + scbK * 8),
                                       (las3_t)(Vs[0] + tid * 8), 16, 0, 0);
      __builtin_amdgcn_global_load_lds((gas1_t)(Vp + (size_t)(srow + 32) * T_ + kv0 + scbK * 8),
                                       (las3_t)(Vs[0] + 2048 + tid * 8), 16, 0, 0);
    }

    for (int c = 0; c < ntile; c++) {
      const int kv0 = c * 64;
      const int cur = c & 1;
      __syncthreads();  // drains own vmcnt -> buf[cur] staged & visible
      if (c + 1 < ntile) {
        const int kv1 = kv0 + 64, nxt = cur ^ 1;
        __builtin_amdgcn_global_load_lds((gas1_t)(Kp + (size_t)(kv1 + srow) * DH + scbK * 8),
                                         (las3_t)(Ks[nxt] + tid * 8), 16, 0, 0);
        __builtin_amdgcn_global_load_lds((gas1_t)(Kp + (size_t)(kv1 + srow + 32) * DH + scbK * 8),
                                         (las3_t)(Ks[nxt] + 2048 + tid * 8), 16, 0, 0);
        __builtin_amdgcn_global_load_lds((gas1_t)(Vp + (size_t)srow * T_ + kv1 + scbK * 8),
                                         (las3_t)(Vs[nxt] + tid * 8), 16, 0, 0);
        __builtin_amdgcn_global_load_lds((gas1_t)(Vp + (size_t)(srow + 32) * T_ + kv1 + scbK * 8),
                                         (las3_t)(Vs[nxt] + 2048 + tid * 8), 16, 0, 0);
      }

      s16x8 kf[4][2];
#pragma unroll
      for (int nt = 0; nt < 4; nt++) {
        const ushort* kr = Ks[cur] + (nt * 16 + l16) * 64;
        kf[nt][0] = *(const s16x8*)(kr + ((quad ^ swz) * 8));
        kf[nt][1] = *(const s16x8*)(kr + (((4 + quad) ^ swz) * 8));
      }
      s16x8 bv[4][2];
#pragma unroll
      for (int dt = 0; dt < 4; dt++) {
        const ushort* vr = Vs[cur] + (dt * 16 + l16) * 64;
        bv[dt][0] = *(const s16x8*)(vr + ((quad ^ swz) * 8));
        bv[dt][1] = *(const s16x8*)(vr + (((4 + quad) ^ swz) * 8));
      }

      // S^T: rows = kv (quad*4+r within nt), cols = q (l16); always active
      f32x4 s[4] = {};
#pragma unroll
      for (int nt = 0; nt < 4; nt++) {
        s[nt] = __builtin_amdgcn_mfma_f32_16x16x32_bf16(kf[nt][0], aq0, s[nt], 0, 0, 0);
        s[nt] = __builtin_amdgcn_mfma_f32_16x16x32_bf16(kf[nt][1], aq1, s[nt], 0, 0, 0);
      }
      if (c < tile) {  // fully unmasked (kv0+63 < 64*tile <= qb)
#pragma unroll
        for (int nt = 0; nt < 4; nt++) {
          float p0 = __builtin_amdgcn_exp2f(fmaf(s[nt][0], EXP2SCALE, -EXP2OFF));
          float p1 = __builtin_amdgcn_exp2f(fmaf(s[nt][1], EXP2SCALE, -EXP2OFF));
          float p2 = __builtin_amdgcn_exp2f(fmaf(s[nt][2], EXP2SCALE, -EXP2OFF));
          float p3 = __builtin_amdgcn_exp2f(fmaf(s[nt][3], EXP2SCALE, -EXP2OFF));
          rsum += (p0 + p1) + (p2 + p3);
          uint2 pk;
          pk.x = cvt_pk_bf16(p0, p1);
          pk.y = cvt_pk_bf16(p2, p3);
          *(uint2*)&P[wave][l16][nt * 16 + quad * 4] = pk;
        }
      } else {  // diagonal tile: mask kv > qi (qi = qb + l16)
        int qi = qb + l16;
#pragma unroll
        for (int nt = 0; nt < 4; nt++) {
          int kvb = kv0 + nt * 16 + quad * 4;
          float pv[4];
#pragma unroll
          for (int r = 0; r < 4; r++)
            pv[r] = (kvb + r <= qi) ? __builtin_amdgcn_exp2f(fmaf(s[nt][r], EXP2SCALE, -EXP2OFF)) : 0.f;
          rsum += (pv[0] + pv[1]) + (pv[2] + pv[3]);
          uint2 pk;
          pk.x = cvt_pk_bf16(pv[0], pv[1]);
          pk.y = cvt_pk_bf16(pv[2], pv[3]);
          *(uint2*)&P[wave][l16][nt * 16 + quad * 4] = pk;
        }
      }
      s16x8 ap0 = *(const s16x8*)&P[wave][l16][quad * 8];
      s16x8 ap1 = *(const s16x8*)&P[wave][l16][32 + quad * 8];
#pragma unroll
      for (int dt = 0; dt < 4; dt++) {
        o[dt] = __builtin_amdgcn_mfma_f32_16x16x32_bf16(ap0, bv[dt][0], o[dt], 0, 0, 0);
        o[dt] = __builtin_amdgcn_mfma_f32_16x16x32_bf16(ap1, bv[dt][1], o[dt], 0, 0, 0);
      }
    }

    // epilogue for this phase: rsum partial (quad's kv slice) for q=l16 -> sum quads
    rsum += __shfl_xor(rsum, 16);
    rsum += __shfl_xor(rsum, 32);
#pragma unroll
    for (int r = 0; r < 4; r++) {
      float inv = 1.0f / __shfl(rsum, quad * 4 + r);  // lane (quad*4+r) holds q-sub = quad*4+r
      int q = qb + quad * 4 + r;
#pragma unroll
      for (int dt = 0; dt < 4; dt++)
        Ob[(size_t)(b * T_ + q) * DM + h * 64 + dt * 16 + l16] = f2b(o[dt][r] * inv);
    }
  }
}

extern "C" void kernel_launch(void* const* d_in, const int* in_sizes, int n_in,
                              void* d_out, int out_size, void* d_ws, size_t ws_size,
                              hipStream_t stream) {
  const float* x = (const float*)d_in[0];
  const float* rc = (const float*)d_in[1];
  const float* rs = (const float*)d_in[2];
  const float* wq = (const float*)d_in[3];
  const float* wk = (const float*)d_in[4];
  const float* wv = (const float*)d_in[5];
  const float* wo = (const float*)d_in[6];

  char* ws = (char*)d_ws;
  ushort* xb   = (ushort*)(ws);                 // 12,582,912
  ushort* wqkv = (ushort*)(ws + 12582912);      //  3,538,944
  ushort* wob  = (ushort*)(ws + 16121856);      //  1,179,648
  float2* cs2  = (float2*)(ws + 17301504);      //    524,288
  ushort* Qb   = (ushort*)(ws + 17825792);      // 12,582,912
  ushort* Kb   = (ushort*)(ws + 30408704);      // 12,582,912
  ushort* Vt   = (ushort*)(ws + 42991616);      // 12,582,912
  ushort* Ob   = (ushort*)(ws + 55574528);      // 12,582,912 (ends ~68.2MB)

  cvt_all<<<8704, 256, 0, stream>>>(x, wq, wk, wv, wo, rc, rs, xb, wqkv, wob, cs2);

  gemm_qkv<<<768, 256, 0, stream>>>(xb, wqkv, cs2, Qb, Kb, Vt);

  attn<<<dim3(48, 16), 256, 0, stream>>>(Qb, Kb, Vt, Ob);

  gemm_out<<<768, 256, 0, stream>>>(Ob, wob, (float*)d_out);
}

// Round 16
// 179.665 us; speedup vs baseline: 1.0767x; 1.0767x over previous
//
#include <hip/hip_runtime.h>
#include <hip/hip_bf16.h>
#include <math.h>

#define B_ 4
#define T_ 2048
#define DM 768
#define H_ 12
#define DH 64

typedef __attribute__((ext_vector_type(4))) float f32x4;
typedef __attribute__((ext_vector_type(8))) short s16x8;

typedef const __attribute__((address_space(1))) void* gas1_t;
typedef __attribute__((address_space(3))) void* las3_t;

__device__ __forceinline__ ushort f2b(float f) {
  union { float f; unsigned u; } v; v.f = f;
  unsigned u = v.u;
  u += 0x7fffu + ((u >> 16) & 1u);
  return (ushort)(u >> 16);
}
// packed f32x2 -> bf16x2 (RNE, same rounding as f2b) in one instruction
__device__ __forceinline__ unsigned cvt_pk_bf16(float lo, float hi) {
  unsigned r;
  asm("v_cvt_pk_bf16_f32 %0, %1, %2" : "=v"(r) : "v"(lo), "v"(hi));
  return r;
}

// ---------------- fused fp32->bf16 conversions + rope pack, one launch ----------------
__global__ void cvt_all(const float* __restrict__ x,
                        const float* __restrict__ wq, const float* __restrict__ wk,
                        const float* __restrict__ wv, const float* __restrict__ wo,
                        const float* __restrict__ rc, const float* __restrict__ rs,
                        ushort* __restrict__ xb, ushort* __restrict__ wqkv,
                        ushort* __restrict__ wob, float2* __restrict__ cs2) {
  const int bid = blockIdx.x, t = threadIdx.x;
  if (bid < 6144) {
    int i = bid * 256 + t;
    float4 v = ((const float4*)x)[i];
    ushort4 o;
    o.x = f2b(v.x); o.y = f2b(v.y); o.z = f2b(v.z); o.w = f2b(v.w);
    ((ushort4*)xb)[i] = o;
  } else if (bid < 8448) {
    int i = (bid - 6144) * 256 + t;  // 0 .. 589823
    int which = i / 147456, j = i - which * 147456;
    const float* src = which == 0 ? wq : which == 1 ? wk : which == 2 ? wv : wo;
    ushort* dst = which < 3 ? wqkv + (size_t)which * 589824 : wob;
    float4 v = ((const float4*)src)[j];
    ushort4 o;
    o.x = f2b(v.x); o.y = f2b(v.y); o.z = f2b(v.z); o.w = f2b(v.w);
    ((ushort4*)dst)[j] = o;
  } else {
    int i = (bid - 8448) * 256 + t;  // 0 .. 65535
    cs2[i] = make_float2(rc[i], rs[i]);
  }
}

// ---------------- QKV GEMM: 128x192 tiles, BK=64, grid 768 = 3/CU exact ----------------
// 768 = 8 XCD x 8 m-panels x 12 n-panels(192). 48 MFMA per barrier pair.
// A staged via global_load_lds from bf16 xb (reg-staged f32 variant was -22us).
__global__ __launch_bounds__(256, 3) void gemm_qkv(
    const ushort* __restrict__ A, const ushort* __restrict__ Bw,
    const float2* __restrict__ cs2,
    ushort* __restrict__ Qb, ushort* __restrict__ Kb, ushort* __restrict__ Vt) {
  const int K = 768;
  __shared__ ushort As[128 * 64];
  __shared__ ushort Bs[192 * 64];
  const int bid = blockIdx.x;
  const int xcd = bid & 7;
  const int jj = bid >> 3;               // 0..95
  const int mloc = jj / 12, nn0 = jj - mloc * 12;
  const int m0 = (xcd * 8 + mloc) * 128, n0 = nn0 * 192;
  const int tid = threadIdx.x;
  const int wave = tid >> 6, lane = tid & 63;
  const int wm = (wave >> 1) * 64, wn = (wave & 1) * 96;
  const int quad = lane >> 4, l16 = lane & 15;
  const int tr = tid >> 3;                 // staging row 0..31 (per 32-row pass)
  const int scb = (tid & 7) ^ (tr & 7);    // pre-swizzled source colblock
  const int swz = l16 & 7;                 // frag-read swizzle term (= row&7)

  f32x4 acc[4][6] = {};

  const ushort* ga = A + (size_t)(m0 + tr) * K + scb * 8;
  const ushort* gb = Bw + (size_t)(n0 + tr) * K + scb * 8;

  for (int k0 = 0; k0 < K; k0 += 64) {
#pragma unroll
    for (int p = 0; p < 4; p++)
      __builtin_amdgcn_global_load_lds((gas1_t)(ga + (size_t)(p * 32) * K + k0),
                                       (las3_t)(As + p * 2048 + tid * 8), 16, 0, 0);
#pragma unroll
    for (int p = 0; p < 6; p++)
      __builtin_amdgcn_global_load_lds((gas1_t)(gb + (size_t)(p * 32) * K + k0),
                                       (las3_t)(Bs + p * 2048 + tid * 8), 16, 0, 0);
    __syncthreads();
#pragma unroll
    for (int kk = 0; kk < 2; kk++) {
      s16x8 af[4], bf[6];
#pragma unroll
      for (int i = 0; i < 4; i++) {
        const ushort* ar = As + (wm + i * 16 + l16) * 64;
        af[i] = *(const s16x8*)(ar + (((kk * 4 + quad) ^ swz) * 8));
      }
#pragma unroll
      for (int n = 0; n < 6; n++) {
        const ushort* br = Bs + (wn + n * 16 + l16) * 64;
        bf[n] = *(const s16x8*)(br + (((kk * 4 + quad) ^ swz) * 8));
      }
#pragma unroll
      for (int i = 0; i < 4; i++)
#pragma unroll
        for (int n = 0; n < 6; n++)
          acc[i][n] = __builtin_amdgcn_mfma_f32_16x16x32_bf16(af[i], bf[n], acc[i][n], 0, 0, 0);
    }
    __syncthreads();
  }

  const int sec = n0 / 768;  // 0=q, 1=k, 2=v (uniform per block; 768 = 4*192)
  if (sec < 2) {
    ushort* dst = sec == 0 ? Qb : Kb;
#pragma unroll
    for (int i = 0; i < 4; i++) {
      int row0 = m0 + wm + i * 16 + quad * 4;
#pragma unroll
      for (int nt = 0; nt < 6; nt++) {
        int col = n0 + wn + nt * 16 + l16;
        int nv = col - sec * 768;
        int h = nv >> 6, d = nv & 63;
        int ip = (d >> 1) & 31;
        float sgn = (d & 1) ? 1.f : -1.f;
#pragma unroll
        for (int r = 0; r < 4; r++) {
          int rrow = row0 + r;
          int t = rrow & (T_ - 1), bb = rrow >> 11;
          float v = acc[i][nt][r];
          float partner = __shfl_xor(v, 1);
          float2 cs = cs2[t * 32 + ip];
          float out = fmaf(v, cs.x, sgn * partner * cs.y);
          dst[((size_t)(bb * H_ + h) * T_ + t) * DH + d] = f2b(out);
        }
      }
    }
  } else {
#pragma unroll
    for (int i = 0; i < 4; i++) {
      int row0 = m0 + wm + i * 16 + quad * 4;
      int t0 = row0 & (T_ - 1), b = row0 >> 11;  // 4 rows share b (aligned)
#pragma unroll
      for (int nt = 0; nt < 6; nt++) {
        int col = n0 + wn + nt * 16 + l16;
        int nv = col - 1536;
        int h = nv >> 6, d = nv & 63;
        ushort4 pk;
        pk.x = f2b(acc[i][nt][0]); pk.y = f2b(acc[i][nt][1]);
        pk.z = f2b(acc[i][nt][2]); pk.w = f2b(acc[i][nt][3]);
        *(ushort4*)(Vt + ((size_t)(b * H_ + h) * DH + d) * T_ + t0) = pk;
      }
    }
  }
}

// ---------------- output GEMM: 128x64 tiles, BK=64, grid 768 = 3/CU exact ----------------
// 768 = 8 XCD x 8 m x 12 n(64).
__global__ __launch_bounds__(256, 3) void gemm_out(
    const ushort* __restrict__ A, const ushort* __restrict__ Bw, float* __restrict__ C) {
  const int K = 768, N = 768;
  __shared__ ushort As[128 * 64];
  __shared__ ushort Bs[64 * 64];
  const int bid = blockIdx.x;
  const int xcd = bid & 7;
  const int jj = bid >> 3;               // 0..95
  const int mloc = jj / 12, nn0 = jj - mloc * 12;
  const int m0 = (xcd * 8 + mloc) * 128, n0 = nn0 * 64;
  const int tid = threadIdx.x;
  const int wave = tid >> 6, lane = tid & 63;
  const int wm = (wave >> 1) * 64, wn = (wave & 1) * 32;
  const int quad = lane >> 4, l16 = lane & 15;
  const int tr = tid >> 3;
  const int scb = (tid & 7) ^ (tr & 7);
  const int swz = l16 & 7;

  f32x4 acc[4][2] = {};

  const ushort* ga = A + (size_t)(m0 + tr) * K + scb * 8;
  const ushort* gb = Bw + (size_t)(n0 + tr) * K + scb * 8;

  for (int k0 = 0; k0 < K; k0 += 64) {
#pragma unroll
    for (int p = 0; p < 4; p++)
      __builtin_amdgcn_global_load_lds((gas1_t)(ga + (size_t)(p * 32) * K + k0),
                                       (las3_t)(As + p * 2048 + tid * 8), 16, 0, 0);
#pragma unroll
    for (int p = 0; p < 2; p++)
      __builtin_amdgcn_global_load_lds((gas1_t)(gb + (size_t)(p * 32) * K + k0),
                                       (las3_t)(Bs + p * 2048 + tid * 8), 16, 0, 0);
    __syncthreads();
#pragma unroll
    for (int kk = 0; kk < 2; kk++) {
      s16x8 af[4], bf[2];
#pragma unroll
      for (int i = 0; i < 4; i++) {
        const ushort* ar = As + (wm + i * 16 + l16) * 64;
        af[i] = *(const s16x8*)(ar + (((kk * 4 + quad) ^ swz) * 8));
      }
#pragma unroll
      for (int n = 0; n < 2; n++) {
        const ushort* br = Bs + (wn + n * 16 + l16) * 64;
        bf[n] = *(const s16x8*)(br + (((kk * 4 + quad) ^ swz) * 8));
      }
#pragma unroll
      for (int i = 0; i < 4; i++)
#pragma unroll
        for (int n = 0; n < 2; n++)
          acc[i][n] = __builtin_amdgcn_mfma_f32_16x16x32_bf16(af[i], bf[n], acc[i][n], 0, 0, 0);
    }
    __syncthreads();
  }

#pragma unroll
  for (int i = 0; i < 4; i++) {
    int row = m0 + wm + i * 16 + quad * 4;
#pragma unroll
    for (int n = 0; n < 2; n++) {
      int col = n0 + wn + n * 16 + l16;
#pragma unroll
      for (int r = 0; r < 4; r++)
        C[(size_t)(row + r) * N + col] = acc[i][n][r];
    }
  }
}

// ---------------- causal flash attention v17: hybrid pairing ----------------
// Block (bh,p) holds tiles A=p and B=31-p; each wave owns 16 rows of EACH.
// One kv sweep over 32-p tiles: frag B every iteration, frag A while c<=p.
// Serial chain = (p+1)*32 + (31-2p)*16 = 528 MFMA for all p (v16's economy)
// in only 32-p (avg 24.5) staging iterations (v11's economy; -26% barriers
// vs v16). Bodies = v16's single-frag compute x2, v11 register layout,
// pitch-72 unswizzled P (only clean-WRITE layout). Bans hold: setprio, O^T
// epilogue, psw swizzles, (256,4) bounds.
#define EXP2SCALE 0.18033688f   /* 0.125 * log2(e) */
#define EXP2OFF  17.312340f     /* 12 * log2(e) */
__global__ __launch_bounds__(256, 3) void attn(const ushort* __restrict__ Qb, const ushort* __restrict__ Kb,
                                               const ushort* __restrict__ Vt, ushort* __restrict__ Ob) {
  const int bh = blockIdx.x;
  const int p = blockIdx.y;        // pair index 0..15: tiles p and 31-p
  const int tid = threadIdx.x, wave = tid >> 6, lane = tid & 63;
  const int quad = lane >> 4, l16 = lane & 15;
  const int b = bh / H_, h = bh % H_;
  const ushort* Qp = Qb + (size_t)bh * T_ * DH;
  const ushort* Kp = Kb + (size_t)bh * T_ * DH;
  const ushort* Vp = Vt + (size_t)bh * DH * T_;

  __shared__ ushort Ks[2][64 * 64];
  __shared__ ushort Vs[2][64 * 64];
  __shared__ ushort P[4][16][72];   // per wave; row = q (l16), col = kv

  const int tileA = p, tileB = 31 - p;
  const int qbA = tileA * 64 + wave * 16;   // this wave's 16 rows of tile A
  const int qbB = tileB * 64 + wave * 16;   // this wave's 16 rows of tile B

  s16x8 aqA0, aqA1, aqB0, aqB1;
  {
    const ushort* qp = Qp + (size_t)(qbA + l16) * DH + quad * 8;
    aqA0 = *(const s16x8*)qp;
    aqA1 = *(const s16x8*)(qp + 32);
    const ushort* qp2 = Qp + (size_t)(qbB + l16) * DH + quad * 8;
    aqB0 = *(const s16x8*)qp2;
    aqB1 = *(const s16x8*)(qp2 + 32);
  }
  f32x4 oA[4] = {}, oB[4] = {};
  float rsA = 0.f, rsB = 0.f;

  const int ntile = 32 - p;  // kv tiles 0..31-p (covers tile B; tile A subsets)
  const int srow = tid >> 3;                   // 0..31
  const int scbK = (tid & 7) ^ (srow & 7);     // swizzled source colblock
  const int swz = (l16 & 7);

  {
    const int kv0 = 0;
    __builtin_amdgcn_global_load_lds((gas1_t)(Kp + (size_t)(kv0 + srow) * DH + scbK * 8),
                                     (las3_t)(Ks[0] + tid * 8), 16, 0, 0);
    __builtin_amdgcn_global_load_lds((gas1_t)(Kp + (size_t)(kv0 + srow + 32) * DH + scbK * 8),
                                     (las3_t)(Ks[0] + 2048 + tid * 8), 16, 0, 0);
    __builtin_amdgcn_global_load_lds((gas1_t)(Vp + (size_t)srow * T_ + kv0 + scbK * 8),
                                     (las3_t)(Vs[0] + tid * 8), 16, 0, 0);
    __builtin_amdgcn_global_load_lds((gas1_t)(Vp + (size_t)(srow + 32) * T_ + kv0 + scbK * 8),
                                     (las3_t)(Vs[0] + 2048 + tid * 8), 16, 0, 0);
  }

  for (int c = 0; c < ntile; c++) {
    const int kv0 = c * 64;
    const int cur = c & 1;
    __syncthreads();  // drains own vmcnt -> buf[cur] staged & visible
    if (c + 1 < ntile) {
      const int kv1 = kv0 + 64, nxt = cur ^ 1;
      __builtin_amdgcn_global_load_lds((gas1_t)(Kp + (size_t)(kv1 + srow) * DH + scbK * 8),
                                       (las3_t)(Ks[nxt] + tid * 8), 16, 0, 0);
      __builtin_amdgcn_global_load_lds((gas1_t)(Kp + (size_t)(kv1 + srow + 32) * DH + scbK * 8),
                                       (las3_t)(Ks[nxt] + 2048 + tid * 8), 16, 0, 0);
      __builtin_amdgcn_global_load_lds((gas1_t)(Vp + (size_t)srow * T_ + kv1 + scbK * 8),
                                       (las3_t)(Vs[nxt] + tid * 8), 16, 0, 0);
      __builtin_amdgcn_global_load_lds((gas1_t)(Vp + (size_t)(srow + 32) * T_ + kv1 + scbK * 8),
                                       (las3_t)(Vs[nxt] + 2048 + tid * 8), 16, 0, 0);
    }

    s16x8 kf[4][2];
#pragma unroll
    for (int nt = 0; nt < 4; nt++) {
      const ushort* kr = Ks[cur] + (nt * 16 + l16) * 64;
      kf[nt][0] = *(const s16x8*)(kr + ((quad ^ swz) * 8));
      kf[nt][1] = *(const s16x8*)(kr + (((4 + quad) ^ swz) * 8));
    }
    s16x8 bv[4][2];
#pragma unroll
    for (int dt = 0; dt < 4; dt++) {
      const ushort* vr = Vs[cur] + (dt * 16 + l16) * 64;
      bv[dt][0] = *(const s16x8*)(vr + ((quad ^ swz) * 8));
      bv[dt][1] = *(const s16x8*)(vr + (((4 + quad) ^ swz) * 8));
    }

    // ---- frag B (always active; guard provably true for c <= 31-p) ----
    {
      f32x4 s[4] = {};
#pragma unroll
      for (int nt = 0; nt < 4; nt++) {
        s[nt] = __builtin_amdgcn_mfma_f32_16x16x32_bf16(kf[nt][0], aqB0, s[nt], 0, 0, 0);
        s[nt] = __builtin_amdgcn_mfma_f32_16x16x32_bf16(kf[nt][1], aqB1, s[nt], 0, 0, 0);
      }
      if (c < tileB) {  // fully unmasked
#pragma unroll
        for (int nt = 0; nt < 4; nt++) {
          float p0 = __builtin_amdgcn_exp2f(fmaf(s[nt][0], EXP2SCALE, -EXP2OFF));
          float p1 = __builtin_amdgcn_exp2f(fmaf(s[nt][1], EXP2SCALE, -EXP2OFF));
          float p2 = __builtin_amdgcn_exp2f(fmaf(s[nt][2], EXP2SCALE, -EXP2OFF));
          float p3 = __builtin_amdgcn_exp2f(fmaf(s[nt][3], EXP2SCALE, -EXP2OFF));
          rsB += (p0 + p1) + (p2 + p3);
          uint2 pk;
          pk.x = cvt_pk_bf16(p0, p1);
          pk.y = cvt_pk_bf16(p2, p3);
          *(uint2*)&P[wave][l16][nt * 16 + quad * 4] = pk;
        }
      } else {  // diagonal tile (c == tileB): mask kv > qi
        int qi = qbB + l16;
#pragma unroll
        for (int nt = 0; nt < 4; nt++) {
          int kvb = kv0 + nt * 16 + quad * 4;
          float pv[4];
#pragma unroll
          for (int r = 0; r < 4; r++)
            pv[r] = (kvb + r <= qi) ? __builtin_amdgcn_exp2f(fmaf(s[nt][r], EXP2SCALE, -EXP2OFF)) : 0.f;
          rsB += (pv[0] + pv[1]) + (pv[2] + pv[3]);
          uint2 pk;
          pk.x = cvt_pk_bf16(pv[0], pv[1]);
          pk.y = cvt_pk_bf16(pv[2], pv[3]);
          *(uint2*)&P[wave][l16][nt * 16 + quad * 4] = pk;
        }
      }
      s16x8 ap0 = *(const s16x8*)&P[wave][l16][quad * 8];
      s16x8 ap1 = *(const s16x8*)&P[wave][l16][32 + quad * 8];
#pragma unroll
      for (int dt = 0; dt < 4; dt++) {
        oB[dt] = __builtin_amdgcn_mfma_f32_16x16x32_bf16(ap0, bv[dt][0], oB[dt], 0, 0, 0);
        oB[dt] = __builtin_amdgcn_mfma_f32_16x16x32_bf16(ap1, bv[dt][1], oB[dt], 0, 0, 0);
      }
    }

    // ---- frag A (active while c <= p; wave-uniform) ----
    if (c <= tileA) {
      f32x4 s[4] = {};
#pragma unroll
      for (int nt = 0; nt < 4; nt++) {
        s[nt] = __builtin_amdgcn_mfma_f32_16x16x32_bf16(kf[nt][0], aqA0, s[nt], 0, 0, 0);
        s[nt] = __builtin_amdgcn_mfma_f32_16x16x32_bf16(kf[nt][1], aqA1, s[nt], 0, 0, 0);
      }
      if (c < tileA) {  // fully unmasked
#pragma unroll
        for (int nt = 0; nt < 4; nt++) {
          float p0 = __builtin_amdgcn_exp2f(fmaf(s[nt][0], EXP2SCALE, -EXP2OFF));
          float p1 = __builtin_amdgcn_exp2f(fmaf(s[nt][1], EXP2SCALE, -EXP2OFF));
          float p2 = __builtin_amdgcn_exp2f(fmaf(s[nt][2], EXP2SCALE, -EXP2OFF));
          float p3 = __builtin_amdgcn_exp2f(fmaf(s[nt][3], EXP2SCALE, -EXP2OFF));
          rsA += (p0 + p1) + (p2 + p3);
          uint2 pk;
          pk.x = cvt_pk_bf16(p0, p1);
          pk.y = cvt_pk_bf16(p2, p3);
          *(uint2*)&P[wave][l16][nt * 16 + quad * 4] = pk;
        }
      } else {  // diagonal tile (c == tileA): mask kv > qi
        int qi = qbA + l16;
#pragma unroll
        for (int nt = 0; nt < 4; nt++) {
          int kvb = kv0 + nt * 16 + quad * 4;
          float pv[4];
#pragma unroll
          for (int r = 0; r < 4; r++)
            pv[r] = (kvb + r <= qi) ? __builtin_amdgcn_exp2f(fmaf(s[nt][r], EXP2SCALE, -EXP2OFF)) : 0.f;
          rsA += (pv[0] + pv[1]) + (pv[2] + pv[3]);
          uint2 pk;
          pk.x = cvt_pk_bf16(pv[0], pv[1]);
          pk.y = cvt_pk_bf16(pv[2], pv[3]);
          *(uint2*)&P[wave][l16][nt * 16 + quad * 4] = pk;
        }
      }
      s16x8 ap0 = *(const s16x8*)&P[wave][l16][quad * 8];
      s16x8 ap1 = *(const s16x8*)&P[wave][l16][32 + quad * 8];
#pragma unroll
      for (int dt = 0; dt < 4; dt++) {
        oA[dt] = __builtin_amdgcn_mfma_f32_16x16x32_bf16(ap0, bv[dt][0], oA[dt], 0, 0, 0);
        oA[dt] = __builtin_amdgcn_mfma_f32_16x16x32_bf16(ap1, bv[dt][1], oA[dt], 0, 0, 0);
      }
    }
  }

  // epilogue B
  rsB += __shfl_xor(rsB, 16);
  rsB += __shfl_xor(rsB, 32);
#pragma unroll
  for (int r = 0; r < 4; r++) {
    float inv = 1.0f / __shfl(rsB, quad * 4 + r);
    int q = qbB + quad * 4 + r;
#pragma unroll
    for (int dt = 0; dt < 4; dt++)
      Ob[(size_t)(b * T_ + q) * DM + h * 64 + dt * 16 + l16] = f2b(oB[dt][r] * inv);
  }
  // epilogue A
  rsA += __shfl_xor(rsA, 16);
  rsA += __shfl_xor(rsA, 32);
#pragma unroll
  for (int r = 0; r < 4; r++) {
    float inv = 1.0f / __shfl(rsA, quad * 4 + r);
    int q = qbA + quad * 4 + r;
#pragma unroll
    for (int dt = 0; dt < 4; dt++)
      Ob[(size_t)(b * T_ + q) * DM + h * 64 + dt * 16 + l16] = f2b(oA[dt][r] * inv);
  }
}

extern "C" void kernel_launch(void* const* d_in, const int* in_sizes, int n_in,
                              void* d_out, int out_size, void* d_ws, size_t ws_size,
                              hipStream_t stream) {
  const float* x = (const float*)d_in[0];
  const float* rc = (const float*)d_in[1];
  const float* rs = (const float*)d_in[2];
  const float* wq = (const float*)d_in[3];
  const float* wk = (const float*)d_in[4];
  const float* wv = (const float*)d_in[5];
  const float* wo = (const float*)d_in[6];

  char* ws = (char*)d_ws;
  ushort* xb   = (ushort*)(ws);                 // 12,582,912
  ushort* wqkv = (ushort*)(ws + 12582912);      //  3,538,944
  ushort* wob  = (ushort*)(ws + 16121856);      //  1,179,648
  float2* cs2  = (float2*)(ws + 17301504);      //    524,288
  ushort* Qb   = (ushort*)(ws + 17825792);      // 12,582,912
  ushort* Kb   = (ushort*)(ws + 30408704);      // 12,582,912
  ushort* Vt   = (ushort*)(ws + 42991616);      // 12,582,912
  ushort* Ob   = (ushort*)(ws + 55574528);      // 12,582,912 (ends ~68.2MB)

  cvt_all<<<8704, 256, 0, stream>>>(x, wq, wk, wv, wo, rc, rs, xb, wqkv, wob, cs2);

  gemm_qkv<<<768, 256, 0, stream>>>(xb, wqkv, cs2, Qb, Kb, Vt);

  attn<<<dim3(48, 16), 256, 0, stream>>>(Qb, Kb, Vt, Ob);

  gemm_out<<<768, 256, 0, stream>>>(Ob, wob, (float*)d_out);
}